// Round 1
// baseline (264.508 us; speedup 1.0000x reference)
//
#include <hip/hip_runtime.h>
#include <math.h>

// ---------------------------------------------------------------------------
// LatentReverb: B=2, C=4, H=64, W=64, L=4096.
// k1: per-batch block; fb/tmp plane in 64KB LDS; 8 sequential reflections;
//     epilogue computes qkv per pixel -> ws.
// k2: head_dim=1 attention: o(q) = sum_k e^{q k} v / sum_k e^{q k}.
// k3: spatial conv3x3 + out_proj + oc 1x1 + dry/wet mix.
// ---------------------------------------------------------------------------

__device__ __forceinline__ float sigf(float v) { return 1.0f / (1.0f + __expf(-v)); }

__global__ __launch_bounds__(512, 2) void reverb_qkv_kernel(
    const float* __restrict__ x,
    const float* __restrict__ refl_w,
    const float* __restrict__ refl_d,
    const float* __restrict__ fb_w,
    const float* __restrict__ fb_b,
    const float* __restrict__ d1_w,
    const float* __restrict__ d1_b,
    const float* __restrict__ d2_w,
    const float* __restrict__ d2_b,
    const float* __restrict__ ipw,
    const float* __restrict__ ipb,
    float* __restrict__ Qg, float* __restrict__ Kg, float* __restrict__ Vg)
{
    __shared__ float4 P[4096];                    // exactly 64 KB
    const int b   = blockIdx.x;                   // batch
    const int tid = threadIdx.x;                  // 0..511
    const int xc  = tid & 63;                     // column
    const int ys  = (tid >> 6) << 3;              // 8 rows per thread

    // Build the 3 non-trivial Gaussian kernels in fp64 (matches numpy K_TABLE
    // after f32 rounding). ~15 double exps, once per thread.
    float ktab[3][7];
    #pragma unroll
    for (int r = 1; r <= 3; ++r) {
        const int ks = 2 * r + 1;
        const int s  = (7 - ks) >> 1;
        const double step = 4.0 / (double)(ks - 1);
        double g[7];
        double sum = 0.0;
        #pragma unroll
        for (int t = 0; t < 7; ++t) {
            if (t < ks) { double u = -2.0 + step * (double)t; g[t] = exp(-u * u); sum += g[t]; }
            else g[t] = 0.0;
        }
        #pragma unroll
        for (int t = 0; t < 7; ++t) ktab[r - 1][t] = 0.0f;
        #pragma unroll
        for (int t = 0; t < 7; ++t)
            if (t < ks) ktab[r - 1][s + t] = (float)(g[t] / sum);
    }

    // fb = 0.1*x ; wet = 0  (registers, thread-owned pixels)
    float4 fb[8], wet[8];
    #pragma unroll
    for (int j = 0; j < 8; ++j) {
        const int base = (b * 4) * 4096 + (ys + j) * 64 + xc;   // channel stride 4096
        float4 v;
        v.x = x[base];
        v.y = x[base + 4096];
        v.z = x[base + 8192];
        v.w = x[base + 12288];
        fb[j]  = make_float4(0.1f * v.x, 0.1f * v.y, 0.1f * v.z, 0.1f * v.w);
        wet[j] = make_float4(0.f, 0.f, 0.f, 0.f);
    }
    #pragma unroll
    for (int j = 0; j < 8; ++j) P[(ys + j) * 64 + xc] = fb[j];
    __syncthreads();

    double w8 = 1.0;    // 0.8**i
    for (int i = 0; i < 8; ++i) {
        int kidx = (int)floorf(refl_d[i] * 0.5f);
        kidx = kidx < 0 ? 0 : (kidx > 3 ? 3 : kidx);

        // ---- vertical 7-tap blur (skip when delta kernel) -> P holds tmp ----
        if (kidx != 0) {                       // wave-uniform branch
            float ktv[7];
            #pragma unroll
            for (int u = 0; u < 7; ++u)
                ktv[u] = (kidx == 1) ? ktab[0][u] : (kidx == 2) ? ktab[1][u] : ktab[2][u];

            float4 col[14];
            #pragma unroll
            for (int t = 0; t < 14; ++t) {
                const int y = ys + t - 3;
                col[t] = (y >= 0 && y < 64) ? P[y * 64 + xc] : make_float4(0.f, 0.f, 0.f, 0.f);
            }
            float4 tmp[8];
            #pragma unroll
            for (int j = 0; j < 8; ++j) {
                float4 a = make_float4(0.f, 0.f, 0.f, 0.f);
                #pragma unroll
                for (int u = 0; u < 7; ++u) {
                    const float w = ktv[u];
                    a.x += w * col[j + u].x;  a.y += w * col[j + u].y;
                    a.z += w * col[j + u].z;  a.w += w * col[j + u].w;
                }
                tmp[j] = a;
            }
            __syncthreads();
            #pragma unroll
            for (int j = 0; j < 8; ++j) P[(ys + j) * 64 + xc] = tmp[j];
            __syncthreads();
        }

        // ---- 3x3 conv (4ch->4ch, zero pad) reading P ----
        float4 acc[8];
        #pragma unroll
        for (int j = 0; j < 8; ++j) acc[j] = make_float4(fb_b[0], fb_b[1], fb_b[2], fb_b[3]);

        #pragma unroll
        for (int ri = 0; ri < 10; ++ri) {                 // input rows ys-1 .. ys+8
            const int y = ys + ri - 1;
            const bool yok = (y >= 0) && (y < 64);
            float4 row[3];
            #pragma unroll
            for (int kx = 0; kx < 3; ++kx) {
                const int xx = xc + kx - 1;
                row[kx] = (yok && xx >= 0 && xx < 64) ? P[y * 64 + xx]
                                                      : make_float4(0.f, 0.f, 0.f, 0.f);
            }
            #pragma unroll
            for (int j = 0; j < 8; ++j) {
                const int ky = ri - j;                     // constant after unroll
                if (ky < 0 || ky > 2) continue;
                #pragma unroll
                for (int kx = 0; kx < 3; ++kx) {
                    const float4 t = row[kx];
                    const float* w0 = fb_w + 0 * 36 + ky * 3 + kx;   // [oc][ic][ky][kx], ic stride 9
                    const float* w1 = fb_w + 1 * 36 + ky * 3 + kx;
                    const float* w2 = fb_w + 2 * 36 + ky * 3 + kx;
                    const float* w3 = fb_w + 3 * 36 + ky * 3 + kx;
                    acc[j].x += w0[0] * t.x + w0[9] * t.y + w0[18] * t.z + w0[27] * t.w;
                    acc[j].y += w1[0] * t.x + w1[9] * t.y + w1[18] * t.z + w1[27] * t.w;
                    acc[j].z += w2[0] * t.x + w2[9] * t.y + w2[18] * t.z + w2[27] * t.w;
                    acc[j].w += w3[0] * t.x + w3[9] * t.y + w3[18] * t.z + w3[27] * t.w;
                }
            }
        }
        __syncthreads();   // all conv reads of P done before overwriting with fb

        // ---- damp MLP, wet/fb update, write fb back to P ----
        const float wgt = sigf(refl_w[i]) * (float)w8;
        #pragma unroll
        for (int j = 0; j < 8; ++j) {
            float4 r = acc[j];
            float h0 = d1_b[0] + d1_w[0] * r.x + d1_w[1] * r.y + d1_w[2] * r.z + d1_w[3] * r.w;
            float h1 = d1_b[1] + d1_w[4] * r.x + d1_w[5] * r.y + d1_w[6] * r.z + d1_w[7] * r.w;
            h0 = h0 * sigf(h0);                 // silu
            h1 = h1 * sigf(h1);
            const float d0 = sigf(d2_b[0] + d2_w[0] * h0 + d2_w[1] * h1);
            const float d1v = sigf(d2_b[1] + d2_w[2] * h0 + d2_w[3] * h1);
            const float d2v = sigf(d2_b[2] + d2_w[4] * h0 + d2_w[5] * h1);
            const float d3v = sigf(d2_b[3] + d2_w[6] * h0 + d2_w[7] * h1);
            r.x *= d0; r.y *= d1v; r.z *= d2v; r.w *= d3v;
            wet[j].x += wgt * r.x;  wet[j].y += wgt * r.y;
            wet[j].z += wgt * r.z;  wet[j].w += wgt * r.w;
            fb[j].x += 0.04f * r.x; fb[j].y += 0.04f * r.y;
            fb[j].z += 0.04f * r.z; fb[j].w += 0.04f * r.w;
            P[(ys + j) * 64 + xc] = fb[j];
        }
        __syncthreads();
        w8 *= 0.8;
    }

    // ---- epilogue: qkv = in_proj(wet) -> ws ----
    #pragma unroll
    for (int j = 0; j < 8; ++j) {
        const int pix = (ys + j) * 64 + xc;
        const float4 wv = wet[j];
        #pragma unroll
        for (int h = 0; h < 4; ++h) {
            const float q = ipb[h]
                + ipw[h * 4 + 0] * wv.x + ipw[h * 4 + 1] * wv.y
                + ipw[h * 4 + 2] * wv.z + ipw[h * 4 + 3] * wv.w;
            const float k = ipb[4 + h]
                + ipw[(4 + h) * 4 + 0] * wv.x + ipw[(4 + h) * 4 + 1] * wv.y
                + ipw[(4 + h) * 4 + 2] * wv.z + ipw[(4 + h) * 4 + 3] * wv.w;
            const float v = ipb[8 + h]
                + ipw[(8 + h) * 4 + 0] * wv.x + ipw[(8 + h) * 4 + 1] * wv.y
                + ipw[(8 + h) * 4 + 2] * wv.z + ipw[(8 + h) * 4 + 3] * wv.w;
            const int o = (b * 4 + h) * 4096 + pix;
            Qg[o] = q; Kg[o] = k; Vg[o] = v;
        }
    }
}

// One block = one (b,h) x 128-query chunk; 256 thr = 128 queries x 2 key halves.
__global__ __launch_bounds__(256) void attn_kernel(
    const float* __restrict__ Qg, const float* __restrict__ Kg,
    const float* __restrict__ Vg, float* __restrict__ OH)
{
    __shared__ float2 KV[4096];      // 32 KB interleaved (k,v)
    __shared__ float  wred[8];
    __shared__ float  partN[256], partD[256];

    const int bh  = blockIdx.x >> 5;        // 0..7
    const int sub = blockIdx.x & 31;        // query chunk
    const int tid = threadIdx.x;

    const float* Kp = Kg + bh * 4096;
    const float* Vp = Vg + bh * 4096;

    float pmax = -3.0e38f, pmin = 3.0e38f;
    for (int t = tid; t < 4096; t += 256) {
        const float kv = Kp[t];
        const float vv = Vp[t];
        KV[t] = make_float2(kv, vv);
        pmax = fmaxf(pmax, kv);
        pmin = fminf(pmin, kv);
    }
    #pragma unroll
    for (int off = 32; off > 0; off >>= 1) {
        pmax = fmaxf(pmax, __shfl_xor(pmax, off, 64));
        pmin = fminf(pmin, __shfl_xor(pmin, off, 64));
    }
    if ((tid & 63) == 0) { wred[tid >> 6] = pmax; wred[4 + (tid >> 6)] = pmin; }
    __syncthreads();
    const float kmax = fmaxf(fmaxf(wred[0], wred[1]), fmaxf(wred[2], wred[3]));
    const float kmin = fminf(fminf(wred[4], wred[5]), fminf(wred[6], wred[7]));

    const int ql = tid & 127;
    const int kh = tid >> 7;
    const int qi = sub * 128 + ql;
    const float q = Qg[bh * 4096 + qi];
    const float m = (q >= 0.0f) ? q * kmax : q * kmin;   // analytic row max

    float num0 = 0.f, num1 = 0.f, den0 = 0.f, den1 = 0.f;
    const int kbase = kh * 2048;
    for (int j = 0; j < 2048; j += 8) {
        #pragma unroll
        for (int u = 0; u < 8; u += 2) {
            const float2 a = KV[kbase + j + u];
            const float2 c = KV[kbase + j + u + 1];
            const float e0 = __expf(__fmaf_rn(q, a.x, -m));
            const float e1 = __expf(__fmaf_rn(q, c.x, -m));
            den0 += e0;  den1 += e1;
            num0 = __fmaf_rn(e0, a.y, num0);
            num1 = __fmaf_rn(e1, c.y, num1);
        }
    }
    partN[tid] = num0 + num1;
    partD[tid] = den0 + den1;
    __syncthreads();
    if (tid < 128) {
        const float n = partN[tid] + partN[tid + 128];
        const float d = partD[tid] + partD[tid + 128];
        OH[bh * 4096 + qi] = n / d;
    }
}

__global__ __launch_bounds__(256) void final_kernel(
    const float* __restrict__ x,
    const float* __restrict__ sc_w, const float* __restrict__ sc_b,
    const float* __restrict__ opw,  const float* __restrict__ opb,
    const float* __restrict__ ocw,  const float* __restrict__ ocb,
    const float* __restrict__ OH,   float* __restrict__ out)
{
    const int g   = blockIdx.x * 256 + threadIdx.x;   // 0..8191 (pixel id)
    const int b   = g >> 12;
    const int pix = g & 4095;
    const int y   = pix >> 6;
    const int xc  = pix & 63;

    float xin[4][3][3];
    #pragma unroll
    for (int ic = 0; ic < 4; ++ic)
        #pragma unroll
        for (int ky = 0; ky < 3; ++ky)
            #pragma unroll
            for (int kx = 0; kx < 3; ++kx) {
                const int yy = y + ky - 1, xx = xc + kx - 1;
                xin[ic][ky][kx] = (yy >= 0 && yy < 64 && xx >= 0 && xx < 64)
                                    ? x[(b * 4 + ic) * 4096 + yy * 64 + xx] : 0.f;
            }

    float sp[8];
    #pragma unroll
    for (int oc = 0; oc < 8; ++oc) {
        float a = sc_b[oc];
        #pragma unroll
        for (int ic = 0; ic < 4; ++ic)
            #pragma unroll
            for (int ky = 0; ky < 3; ++ky)
                #pragma unroll
                for (int kx = 0; kx < 3; ++kx)
                    a += sc_w[(oc * 4 + ic) * 9 + ky * 3 + kx] * xin[ic][ky][kx];
        sp[oc] = a;
    }

    float oh[4];
    #pragma unroll
    for (int h = 0; h < 4; ++h) oh[h] = OH[(b * 4 + h) * 4096 + pix];

    float w2[4];
    #pragma unroll
    for (int c = 0; c < 4; ++c)
        w2[c] = opb[c] + opw[c * 4 + 0] * oh[0] + opw[c * 4 + 1] * oh[1]
                       + opw[c * 4 + 2] * oh[2] + opw[c * 4 + 3] * oh[3];

    #pragma unroll
    for (int c = 0; c < 4; ++c) {
        float a = ocb[c];
        #pragma unroll
        for (int j = 0; j < 8; ++j) a += ocw[c * 12 + j] * sp[j];
        #pragma unroll
        for (int h = 0; h < 4; ++h) a += ocw[c * 12 + 8 + h] * w2[h];
        const int idx = (b * 4 + c) * 4096 + y * 64 + xc;
        out[idx] = 0.7f * x[idx] + 0.3f * a;
    }
}

extern "C" void kernel_launch(void* const* d_in, const int* in_sizes, int n_in,
                              void* d_out, int out_size, void* d_ws, size_t ws_size,
                              hipStream_t stream) {
    const float* x      = (const float*)d_in[0];
    const float* refl_w = (const float*)d_in[1];
    const float* refl_d = (const float*)d_in[2];
    const float* sc_w   = (const float*)d_in[3];
    const float* sc_b   = (const float*)d_in[4];
    const float* fb_w   = (const float*)d_in[5];
    const float* fb_b   = (const float*)d_in[6];
    const float* d1_w   = (const float*)d_in[7];
    const float* d1_b   = (const float*)d_in[8];
    const float* d2_w   = (const float*)d_in[9];
    const float* d2_b   = (const float*)d_in[10];
    const float* ipw    = (const float*)d_in[11];
    const float* ipb    = (const float*)d_in[12];
    const float* opw    = (const float*)d_in[13];
    const float* opb    = (const float*)d_in[14];
    const float* ocw    = (const float*)d_in[15];
    const float* ocb    = (const float*)d_in[16];
    float* out = (float*)d_out;

    float* Q  = (float*)d_ws;           // [8][4096]
    float* K  = Q + 32768;
    float* V  = K + 32768;
    float* OH = V + 32768;

    reverb_qkv_kernel<<<dim3(2), dim3(512), 0, stream>>>(
        x, refl_w, refl_d, fb_w, fb_b, d1_w, d1_b, d2_w, d2_b, ipw, ipb, Q, K, V);
    attn_kernel<<<dim3(256), dim3(256), 0, stream>>>(Q, K, V, OH);
    final_kernel<<<dim3(32), dim3(256), 0, stream>>>(
        x, sc_w, sc_b, opw, opb, ocw, ocb, OH, out);
}

// Round 3
// 192.228 us; speedup vs baseline: 1.3760x; 1.3760x over previous
//
#include <hip/hip_runtime.h>
#include <math.h>

// ---------------------------------------------------------------------------
// LatentReverb: B=2, C=4, H=64, W=64, L=4096.
// k1: 32 blocks (16 slabs x 2 batches); DOUBLE-BUFFERED fb plane in ws
//     (agent-scope atomic ld/st), one grid barrier per reflection.
//     buf0 overlays the Q region (dead before epilogue writes Q).
// k2: head_dim=1 attention, 512 blocks, float4 broadcast KV reads from LDS.
// k3: spatial conv3x3 + out_proj + oc 1x1 + dry/wet mix.
// ---------------------------------------------------------------------------

#define NBLK 32u   // reverb grid: co-resident trivially on 256 CUs

typedef unsigned long long u64;

__device__ __forceinline__ float sigf(float v) { return 1.0f / (1.0f + __expf(-v)); }

// coherent-point float4 load/store (two 8B agent-scope relaxed atomics)
__device__ __forceinline__ float4 ld_fb(const float4* p) {
    const u64* q = (const u64*)p;
    u64 a = __hip_atomic_load(q,     __ATOMIC_RELAXED, __HIP_MEMORY_SCOPE_AGENT);
    u64 b = __hip_atomic_load(q + 1, __ATOMIC_RELAXED, __HIP_MEMORY_SCOPE_AGENT);
    float2 lo = *(float2*)&a, hi = *(float2*)&b;
    return make_float4(lo.x, lo.y, hi.x, hi.y);
}
__device__ __forceinline__ void st_fb(float4* p, float4 v) {
    u64* q = (u64*)p;
    float2 lo = make_float2(v.x, v.y), hi = make_float2(v.z, v.w);
    __hip_atomic_store(q,     *(u64*)&lo, __ATOMIC_RELAXED, __HIP_MEMORY_SCOPE_AGENT);
    __hip_atomic_store(q + 1, *(u64*)&hi, __ATOMIC_RELAXED, __HIP_MEMORY_SCOPE_AGENT);
}

__device__ __forceinline__ void grid_barrier(unsigned* cnt, unsigned target) {
    __threadfence();                      // release: L2 writeback to coherent pt
    __syncthreads();                      // per-wave vmcnt(0) drain + block sync
    if (threadIdx.x == 0) {
        __hip_atomic_fetch_add(cnt, 1u, __ATOMIC_ACQ_REL, __HIP_MEMORY_SCOPE_AGENT);
        while (__hip_atomic_load(cnt, __ATOMIC_RELAXED, __HIP_MEMORY_SCOPE_AGENT) < target) { }
    }
    __syncthreads();
    __threadfence();                      // acquire: invalidate L1/L2
}

__global__ __launch_bounds__(256, 4) void reverb_qkv_kernel(
    const float* __restrict__ x,
    const float* __restrict__ refl_w,
    const float* __restrict__ refl_d,
    const float* __restrict__ fb_w,
    const float* __restrict__ fb_b,
    const float* __restrict__ d1_w,
    const float* __restrict__ d1_b,
    const float* __restrict__ d2_w,
    const float* __restrict__ d2_b,
    const float* __restrict__ ipw,
    const float* __restrict__ ipb,
    float4* buf0, float4* buf1,       // fb ping-pong planes [2][4096] (no restrict: buf0 aliases Qg)
    unsigned* bar,
    float* Qg, float* Kg, float* Vg)
{
    __shared__ float4 HB[12 * 64];    // fb halo rows r0-4 .. r0+7
    __shared__ float4 BL[6 * 64];     // blurred rows r0-1 .. r0+4

    const int blk   = blockIdx.x;
    const int batch = blk >> 4;
    const int slab  = blk & 15;
    const int r0    = slab << 2;      // 4 rows per block
    const int tid   = threadIdx.x;
    const int ty    = tid >> 6;       // 0..3
    const int xc    = tid & 63;
    const int y     = r0 + ty;
    const int pix   = y * 64 + xc;

    // Gaussian kernel table in fp64 (matches numpy K_TABLE after f32 round).
    float ktab[4][7];
    #pragma unroll
    for (int u = 0; u < 7; ++u) ktab[0][u] = (u == 3) ? 1.0f : 0.0f;
    #pragma unroll
    for (int r = 1; r <= 3; ++r) {
        const int ks = 2 * r + 1;
        const int s  = (7 - ks) >> 1;
        const double step = 4.0 / (double)(ks - 1);
        double g[7]; double sum = 0.0;
        #pragma unroll
        for (int t = 0; t < 7; ++t) {
            if (t < ks) { double u = -2.0 + step * (double)t; g[t] = exp(-u * u); sum += g[t]; }
            else g[t] = 0.0;
        }
        #pragma unroll
        for (int t = 0; t < 7; ++t) ktab[r][t] = 0.0f;
        #pragma unroll
        for (int t = 0; t < 7; ++t)
            if (t < ks) ktab[r][s + t] = (float)(g[t] / sum);
    }

    // init: fb = 0.1 * x for owned pixel -> buf0
    const int xbase = (batch * 4) * 4096 + pix;
    float4 fbreg;
    fbreg.x = 0.1f * x[xbase];
    fbreg.y = 0.1f * x[xbase + 4096];
    fbreg.z = 0.1f * x[xbase + 8192];
    fbreg.w = 0.1f * x[xbase + 12288];
    float4 wet = make_float4(0.f, 0.f, 0.f, 0.f);
    st_fb(buf0 + batch * 4096 + pix, fbreg);
    grid_barrier(bar, NBLK);                      // phase 1

    double w8 = 1.0;   // 0.8**i in double, cast at use
    for (int i = 0; i < 8; ++i) {
        const float4* src = (i & 1) ? buf1 : buf0;   // read state i
        float4*       dst = (i & 1) ? buf0 : buf1;   // write state i+1

        int kidx = (int)floorf(refl_d[i] * 0.5f);
        kidx = kidx < 0 ? 0 : (kidx > 3 ? 3 : kidx);

        // ---- stage fb halo rows r0-4 .. r0+7 from src ----
        for (int t = tid; t < 768; t += 256) {
            const int hr = t >> 6, col = t & 63;
            const int gy = r0 - 4 + hr;
            HB[t] = (gy >= 0 && gy < 64) ? ld_fb(src + batch * 4096 + gy * 64 + col)
                                         : make_float4(0.f, 0.f, 0.f, 0.f);
        }
        __syncthreads();

        // ---- vertical 7-tap blur, rows r0-1 .. r0+4 ----
        if (tid < 384) {
            const int br = tid >> 6, col = tid & 63;
            const int gy = r0 - 1 + br;
            float4 a = make_float4(0.f, 0.f, 0.f, 0.f);
            if (gy >= 0 && gy < 64) {
                #pragma unroll
                for (int u = 0; u < 7; ++u) {
                    const float w = ktab[kidx][u];
                    const float4 t4 = HB[(br + u) * 64 + col];
                    a.x += w * t4.x; a.y += w * t4.y; a.z += w * t4.z; a.w += w * t4.w;
                }
            }
            BL[br * 64 + col] = a;
        }
        __syncthreads();

        // ---- 3x3 conv (4ch->4ch, zero pad) on blurred rows ----
        float4 acc = make_float4(fb_b[0], fb_b[1], fb_b[2], fb_b[3]);
        #pragma unroll
        for (int ky = 0; ky < 3; ++ky) {
            #pragma unroll
            for (int kx = 0; kx < 3; ++kx) {
                const int xx = xc + kx - 1;
                const float4 t = (xx >= 0 && xx < 64) ? BL[(ty + ky) * 64 + xx]
                                                      : make_float4(0.f, 0.f, 0.f, 0.f);
                const float* w0 = fb_w + 0 * 36 + ky * 3 + kx;  // [oc][ic][3][3]
                const float* w1 = fb_w + 1 * 36 + ky * 3 + kx;
                const float* w2 = fb_w + 2 * 36 + ky * 3 + kx;
                const float* w3 = fb_w + 3 * 36 + ky * 3 + kx;
                acc.x += w0[0] * t.x + w0[9] * t.y + w0[18] * t.z + w0[27] * t.w;
                acc.y += w1[0] * t.x + w1[9] * t.y + w1[18] * t.z + w1[27] * t.w;
                acc.z += w2[0] * t.x + w2[9] * t.y + w2[18] * t.z + w2[27] * t.w;
                acc.w += w3[0] * t.x + w3[9] * t.y + w3[18] * t.z + w3[27] * t.w;
            }
        }

        // ---- damp MLP, wet/fb update ----
        const float wgt = sigf(refl_w[i]) * (float)w8;
        {
            float4 r = acc;
            float h0 = d1_b[0] + d1_w[0] * r.x + d1_w[1] * r.y + d1_w[2] * r.z + d1_w[3] * r.w;
            float h1 = d1_b[1] + d1_w[4] * r.x + d1_w[5] * r.y + d1_w[6] * r.z + d1_w[7] * r.w;
            h0 = h0 * sigf(h0);
            h1 = h1 * sigf(h1);
            const float d0 = sigf(d2_b[0] + d2_w[0] * h0 + d2_w[1] * h1);
            const float d1v = sigf(d2_b[1] + d2_w[2] * h0 + d2_w[3] * h1);
            const float d2v = sigf(d2_b[2] + d2_w[4] * h0 + d2_w[5] * h1);
            const float d3v = sigf(d2_b[3] + d2_w[6] * h0 + d2_w[7] * h1);
            r.x *= d0; r.y *= d1v; r.z *= d2v; r.w *= d3v;
            wet.x += wgt * r.x;  wet.y += wgt * r.y;
            wet.z += wgt * r.z;  wet.w += wgt * r.w;
            fbreg.x += 0.04f * r.x; fbreg.y += 0.04f * r.y;
            fbreg.z += 0.04f * r.z; fbreg.w += 0.04f * r.w;
        }
        if (i < 7) {
            st_fb(dst + batch * 4096 + pix, fbreg);   // publish state i+1
            grid_barrier(bar, (unsigned)(i + 2) * NBLK);
        }
        w8 *= 0.8;
    }

    // ---- epilogue: qkv = in_proj(wet) ----
    // Qg aliases buf0: safe, buf0 dead after the iter-6 barrier.
    #pragma unroll
    for (int h = 0; h < 4; ++h) {
        const float q = ipb[h]
            + ipw[h * 4 + 0] * wet.x + ipw[h * 4 + 1] * wet.y
            + ipw[h * 4 + 2] * wet.z + ipw[h * 4 + 3] * wet.w;
        const float k = ipb[4 + h]
            + ipw[(4 + h) * 4 + 0] * wet.x + ipw[(4 + h) * 4 + 1] * wet.y
            + ipw[(4 + h) * 4 + 2] * wet.z + ipw[(4 + h) * 4 + 3] * wet.w;
        const float v = ipb[8 + h]
            + ipw[(8 + h) * 4 + 0] * wet.x + ipw[(8 + h) * 4 + 1] * wet.y
            + ipw[(8 + h) * 4 + 2] * wet.z + ipw[(8 + h) * 4 + 3] * wet.w;
        const int o = (batch * 4 + h) * 4096 + pix;
        Qg[o] = q; Kg[o] = k; Vg[o] = v;
    }
}

// 512 blocks: (b,h) x 64-query chunk; 256 thr = 64 queries x 4 key quarters.
__global__ __launch_bounds__(256) void attn_kernel(
    const float* __restrict__ Qg, const float* __restrict__ Kg,
    const float* __restrict__ Vg, float* __restrict__ OH)
{
    __shared__ float2 KV[4096];      // 32 KB interleaved (k,v)
    __shared__ float  wred[8];
    __shared__ float  partN[256], partD[256];

    const int bh  = blockIdx.x >> 6;        // 0..7
    const int sub = blockIdx.x & 63;        // query chunk
    const int tid = threadIdx.x;

    const float* Kp = Kg + bh * 4096;
    const float* Vp = Vg + bh * 4096;

    float pmax = -3.0e38f, pmin = 3.0e38f;
    for (int t = tid; t < 4096; t += 256) {
        const float kv = Kp[t];
        const float vv = Vp[t];
        KV[t] = make_float2(kv, vv);
        pmax = fmaxf(pmax, kv);
        pmin = fminf(pmin, kv);
    }
    #pragma unroll
    for (int off = 32; off > 0; off >>= 1) {
        pmax = fmaxf(pmax, __shfl_xor(pmax, off, 64));
        pmin = fminf(pmin, __shfl_xor(pmin, off, 64));
    }
    if ((tid & 63) == 0) { wred[tid >> 6] = pmax; wred[4 + (tid >> 6)] = pmin; }
    __syncthreads();
    const float kmax = fmaxf(fmaxf(wred[0], wred[1]), fmaxf(wred[2], wred[3]));
    const float kmin = fminf(fminf(wred[4], wred[5]), fminf(wred[6], wred[7]));

    const int ql = tid & 63;
    const int kh = tid >> 6;               // key quarter (1024 keys)
    const int qi = sub * 64 + ql;
    const float q = Qg[bh * 4096 + qi];
    const float m = (q >= 0.0f) ? q * kmax : q * kmin;   // analytic row max

    const float4* KV4 = (const float4*)KV;  // (k0,v0,k1,v1) per element
    const int base4 = kh * 512;             // 1024 keys = 512 float4

    float num0 = 0.f, num1 = 0.f, den0 = 0.f, den1 = 0.f;
    for (int j = 0; j < 512; j += 4) {
        #pragma unroll
        for (int u = 0; u < 4; ++u) {
            const float4 f = KV4[base4 + j + u];
            const float e0 = __expf(__fmaf_rn(q, f.x, -m));
            const float e1 = __expf(__fmaf_rn(q, f.z, -m));
            den0 += e0;  den1 += e1;
            num0 = __fmaf_rn(e0, f.y, num0);
            num1 = __fmaf_rn(e1, f.w, num1);
        }
    }
    partN[tid] = num0 + num1;
    partD[tid] = den0 + den1;
    __syncthreads();
    if (tid < 64) {
        const float n = partN[tid] + partN[tid + 64] + partN[tid + 128] + partN[tid + 192];
        const float d = partD[tid] + partD[tid + 64] + partD[tid + 128] + partD[tid + 192];
        OH[bh * 4096 + sub * 64 + tid] = n / d;
    }
}

__global__ __launch_bounds__(256) void final_kernel(
    const float* __restrict__ x,
    const float* __restrict__ sc_w, const float* __restrict__ sc_b,
    const float* __restrict__ opw,  const float* __restrict__ opb,
    const float* __restrict__ ocw,  const float* __restrict__ ocb,
    const float* __restrict__ OH,   float* __restrict__ out)
{
    const int g   = blockIdx.x * 256 + threadIdx.x;   // 0..8191 (pixel id)
    const int b   = g >> 12;
    const int pix = g & 4095;
    const int y   = pix >> 6;
    const int xc  = pix & 63;

    float xin[4][3][3];
    #pragma unroll
    for (int ic = 0; ic < 4; ++ic)
        #pragma unroll
        for (int ky = 0; ky < 3; ++ky)
            #pragma unroll
            for (int kx = 0; kx < 3; ++kx) {
                const int yy = y + ky - 1, xx = xc + kx - 1;
                xin[ic][ky][kx] = (yy >= 0 && yy < 64 && xx >= 0 && xx < 64)
                                    ? x[(b * 4 + ic) * 4096 + yy * 64 + xx] : 0.f;
            }

    float sp[8];
    #pragma unroll
    for (int oc = 0; oc < 8; ++oc) {
        float a = sc_b[oc];
        #pragma unroll
        for (int ic = 0; ic < 4; ++ic)
            #pragma unroll
            for (int ky = 0; ky < 3; ++ky)
                #pragma unroll
                for (int kx = 0; kx < 3; ++kx)
                    a += sc_w[(oc * 4 + ic) * 9 + ky * 3 + kx] * xin[ic][ky][kx];
        sp[oc] = a;
    }

    float oh[4];
    #pragma unroll
    for (int h = 0; h < 4; ++h) oh[h] = OH[(b * 4 + h) * 4096 + pix];

    float w2[4];
    #pragma unroll
    for (int c = 0; c < 4; ++c)
        w2[c] = opb[c] + opw[c * 4 + 0] * oh[0] + opw[c * 4 + 1] * oh[1]
                       + opw[c * 4 + 2] * oh[2] + opw[c * 4 + 3] * oh[3];

    #pragma unroll
    for (int c = 0; c < 4; ++c) {
        float a = ocb[c];
        #pragma unroll
        for (int j = 0; j < 8; ++j) a += ocw[c * 12 + j] * sp[j];
        #pragma unroll
        for (int h = 0; h < 4; ++h) a += ocw[c * 12 + 8 + h] * w2[h];
        const int idx = (b * 4 + c) * 4096 + y * 64 + xc;
        out[idx] = 0.7f * x[idx] + 0.3f * a;
    }
}

extern "C" void kernel_launch(void* const* d_in, const int* in_sizes, int n_in,
                              void* d_out, int out_size, void* d_ws, size_t ws_size,
                              hipStream_t stream) {
    const float* x      = (const float*)d_in[0];
    const float* refl_w = (const float*)d_in[1];
    const float* refl_d = (const float*)d_in[2];
    const float* sc_w   = (const float*)d_in[3];
    const float* sc_b   = (const float*)d_in[4];
    const float* fb_w   = (const float*)d_in[5];
    const float* fb_b   = (const float*)d_in[6];
    const float* d1_w   = (const float*)d_in[7];
    const float* d1_b   = (const float*)d_in[8];
    const float* d2_w   = (const float*)d_in[9];
    const float* d2_b   = (const float*)d_in[10];
    const float* ipw    = (const float*)d_in[11];
    const float* ipb    = (const float*)d_in[12];
    const float* opw    = (const float*)d_in[13];
    const float* opb    = (const float*)d_in[14];
    const float* ocw    = (const float*)d_in[15];
    const float* ocb    = (const float*)d_in[16];
    float* out = (float*)d_out;

    // ws layout (640 KB + 4):
    //   [buf0 / Q : 128 KB][buf1 : 128 KB][K : 128 KB][V : 128 KB][OH : 128 KB][bar]
    float4*   buf0 = (float4*)d_ws;
    float4*   buf1 = buf0 + 8192;
    float*    Q    = (float*)d_ws;                 // aliases buf0 (dead by epilogue)
    float*    K    = (float*)d_ws + 65536;
    float*    V    = K + 32768;
    float*    OH   = V + 32768;
    unsigned* bar  = (unsigned*)(OH + 32768);

    hipMemsetAsync(bar, 0, sizeof(unsigned), stream);

    reverb_qkv_kernel<<<dim3(NBLK), dim3(256), 0, stream>>>(
        x, refl_w, refl_d, fb_w, fb_b, d1_w, d1_b, d2_w, d2_b, ipw, ipb,
        buf0, buf1, bar, Q, K, V);
    attn_kernel<<<dim3(512), dim3(256), 0, stream>>>(Q, K, V, OH);
    final_kernel<<<dim3(32), dim3(256), 0, stream>>>(
        x, sc_w, sc_b, opw, opb, ocw, ocb, OH, out);
}